// Round 10
// baseline (392.619 us; speedup 1.0000x reference)
//
#include <hip/hip_runtime.h>
#include <hip/hip_bf16.h>

using short8 = __attribute__((ext_vector_type(8))) short;
using f32x4  = __attribute__((ext_vector_type(4))) float;

typedef const __attribute__((address_space(1))) void* gvp;
typedef __attribute__((address_space(3))) void* lvp;

#define NB   64     // batch rows (M)
#define NTOK 32     // tokens per batch row
#define DD   384
#define NE   8      // experts
#define TK   8      // top-k
#define NC   1000
#define KD   3072   // K*D
#define ND   12288  // N*D

__device__ __forceinline__ float gelu_f(float x) {
  return 0.5f * x * (1.0f + erff(x * 0.70710678118654752440f));
}

// f32 -> bf16 round-to-nearest-even (bit trick)
__device__ __forceinline__ unsigned short f2bf(float f) {
  unsigned u = __float_as_uint(f);
  u += 0x7fffu + ((u >> 16) & 1u);
  return (unsigned short)(u >> 16);
}

// ---------------------------------------------------------------------------
// Routing: logits = x[b] @ emb^T, top-8 per (b,e) (softmax monotonic -> skip),
// gather sel[e][b][k*D+d] = bf16(x[b][I[b,e,k]][d]); also xb = bf16(x).
// ---------------------------------------------------------------------------
__global__ __launch_bounds__(256) void routing_kernel(
    const float* __restrict__ x, const float* __restrict__ emb,
    unsigned short* __restrict__ sel, unsigned short* __restrict__ xb)
{
  __shared__ float xs[NTOK][DD + 1];   // +1 pad: kill stride-384 bank conflicts
  __shared__ float es[NE][DD + 1];
  __shared__ float lg[NE][NTOK];
  __shared__ int   Is[NE][TK];
  const int b = blockIdx.x, tid = threadIdx.x;

  for (int i = tid; i < NTOK * DD; i += 256) xs[i / DD][i % DD] = x[(size_t)b * ND + i];
  for (int i = tid; i < NE * DD;   i += 256) es[i / DD][i % DD] = emb[i];
  __syncthreads();

  {
    const int e = tid >> 5, n = tid & 31;
    float s = 0.f;
    for (int d = 0; d < DD; ++d) s += xs[n][d] * es[e][d];
    lg[e][n] = s;
  }
  __syncthreads();

  if (tid < NE) {   // stable argmax x8: ties -> lowest index, matches lax.top_k
    const int e = tid;
    for (int k = 0; k < TK; ++k) {
      float best = lg[e][0]; int bi = 0;
      for (int n = 1; n < NTOK; ++n) { float v = lg[e][n]; if (v > best) { best = v; bi = n; } }
      Is[e][k] = bi;
      lg[e][bi] = -INFINITY;
    }
  }
  __syncthreads();

  for (int i = tid; i < NE * KD; i += 256) {
    const int e = i / KD, r = i % KD, k = r / DD, d = r % DD;
    const int n = Is[e][k];
    sel[((size_t)e * NB + b) * KD + r] = f2bf(xs[n][d]);
  }
  for (int i = tid; i < ND; i += 256) xb[(size_t)b * ND + i] = f2bf(xs[i / DD][i % DD]);
}

// ---------------------------------------------------------------------------
// Runtime-parameter GEMM body (r2's proven 64x128 double-buffer schedule).
// FUSED=false: f32 partial store to opf (row stride N).
// FUSED=true : out = bf16(gelu(acc + bias[col])) to opb (row stride N).
// ---------------------------------------------------------------------------
template<bool FUSED>
__device__ __forceinline__ void gemm_rt_body(
    const unsigned short* __restrict__ Ab, const float* __restrict__ Wz,
    const int K, const int N, const int NSTEP, const int n0,
    const int wv, const int lane, float* __restrict__ lw,
    float* __restrict__ opf, unsigned short* __restrict__ opb,
    const float* __restrict__ bias)
{
  // staging geometry: instr r of wave wv -> rows wv*8 + r*2 + (lane>>5),
  // stored col (lane&31)*4; source col = (stored - wv*8) & 127
  const int srow = wv * 8 + (lane >> 5);
  const int scol = (((lane & 31) * 4) - wv * 8) & 127;
  const float* gsrc = Wz + (size_t)srow * N + n0 + scol;
  float* lbase = lw + wv * 1024 + lane * 4;

  auto stage = [&](int bf, int st) {
    const float* g = gsrc + (size_t)st * 32 * N;
    float* l = lbase + bf * 4096;
    #pragma unroll
    for (int r = 0; r < 4; ++r)
      __builtin_amdgcn_global_load_lds((gvp)(g + (size_t)(r * 2) * N),
                                       (lvp)(l + r * 256), 16, 0, 0);
  };

  const int ln = lane & 15, q = lane >> 4, g8 = q * 8;
  const unsigned short* ap = Ab + (size_t)ln * K + g8;
  const int colp0 = (wv * 32 +      ln + g8) & 127;
  const int colp1 = (wv * 32 + 16 + ln + g8) & 127;

  f32x4 acc[4][2];
  #pragma unroll
  for (int mt = 0; mt < 4; ++mt) {
    acc[mt][0] = (f32x4){0.f, 0.f, 0.f, 0.f};
    acc[mt][1] = (f32x4){0.f, 0.f, 0.f, 0.f};
  }

  stage(0, 0);
  for (int st = 0; st < NSTEP; ++st) {
    const int bf = st & 1;
    __syncthreads();                      // drains stage(st); readers of bf^1 done
    if (st + 1 < NSTEP) stage(bf ^ 1, st + 1);

    const float* lb = lw + bf * 4096;
    union { short8 v; unsigned short u[8]; } pb0, pb1;
    #pragma unroll
    for (int j = 0; j < 8; ++j) {
      pb0.u[j] = f2bf(lb[(g8 + j) * 128 + colp0]);
      pb1.u[j] = f2bf(lb[(g8 + j) * 128 + colp1]);
    }
    #pragma unroll
    for (int mt = 0; mt < 4; ++mt) {
      const short8 afr = *reinterpret_cast<const short8*>(ap + (size_t)mt * 16 * K + st * 32);
      acc[mt][0] = __builtin_amdgcn_mfma_f32_16x16x32_bf16(afr, pb0.v, acc[mt][0], 0, 0, 0);
      acc[mt][1] = __builtin_amdgcn_mfma_f32_16x16x32_bf16(afr, pb1.v, acc[mt][1], 0, 0, 0);
    }
  }

  // epilogue (C/D: col = ln, row = q*4 + reg)
  #pragma unroll
  for (int mt = 0; mt < 4; ++mt)
    #pragma unroll
    for (int s = 0; s < 2; ++s) {
      const int col = n0 + wv * 32 + s * 16 + ln;
      #pragma unroll
      for (int r = 0; r < 4; ++r) {
        const int row = mt * 16 + q * 4 + r;
        if (FUSED) {
          const float v = gelu_f(acc[mt][s][r] + bias[col]);
          opb[(size_t)row * N + col] = f2bf(v);
        } else {
          opf[(size_t)row * N + col] = acc[mt][s][r];
        }
      }
    }
}

// ---------------------------------------------------------------------------
// Phase A (576 uniform blocks, NSTEP=96):
//   rem 0   : expert GEMM1, z=1, fused gelu+b1 -> h (bf16)   [192 blocks]
//   rem 1,2 : sw GEMM1, z in [0,4), f32 partials -> tpt      [384 blocks]
// ---------------------------------------------------------------------------
__global__ __launch_bounds__(256) void dualA_kernel(
    const unsigned short* __restrict__ sel, const float* __restrict__ w1,
    const float* __restrict__ b1, unsigned short* __restrict__ h,
    const unsigned short* __restrict__ xb, const float* __restrict__ sww1,
    float* __restrict__ tpt)
{
  __shared__ float lw[2][4096];
  const int t = threadIdx.x, wv = t >> 6, lane = t & 63;
  const int bid = blockIdx.x;
  const int grp = bid / 3, rem = bid - grp * 3;

  if (rem == 0) {
    // EG1: idx in [0,192): bt = idx&7, nx = idx>>3 in [0,24)
    const int idx = grp;
    const int bt = idx & 7, nx = idx >> 3;
    gemm_rt_body<true>(sel + (size_t)bt * 64 * KD,
                       w1 + (size_t)bt * KD * KD,
                       KD, KD, KD / 32, nx * 128, wv, lane, &lw[0][0],
                       nullptr, h + (size_t)bt * 64 * KD, b1 + (size_t)bt * KD);
  } else {
    // sw: idx in [0,384): z = idx&3 in [0,4), nx = idx>>2 in [0,96)
    const int idx = grp * 2 + (rem - 1);
    const int z = idx & 3, nx = idx >> 2;
    constexpr int KCH = ND / 4;   // 3072, NSTEP = 96
    gemm_rt_body<false>(xb + (size_t)z * KCH,
                        sww1 + (size_t)z * KCH * ND,
                        ND, ND, KCH / 32, nx * 128, wv, lane, &lw[0][0],
                        tpt + (size_t)z * 64 * ND, nullptr, nullptr);
  }
}

// ---------------------------------------------------------------------------
// Phase B (1152 blocks):
//   rem 0   : expert GEMM2, z=2 (NSTEP=48), f32 partials -> ep  [384 blocks]
//   rem 1,2 : sw gate partial dots (b,slice), tpt z<4 -> pd     [768 blocks]
// Short pd blocks drain early; tail is uniform EG2 blocks.
// ---------------------------------------------------------------------------
__global__ __launch_bounds__(256) void dualB_kernel(
    const unsigned short* __restrict__ h, const float* __restrict__ w2,
    float* __restrict__ ep,
    const float* __restrict__ tpt, const float* __restrict__ swb1,
    const float* __restrict__ sww2, float* __restrict__ pd)
{
  __shared__ float lw[2][4096];
  const int t = threadIdx.x, wv = t >> 6, lane = t & 63;
  const int bid = blockIdx.x;
  const int grp = bid / 3, rem = bid - grp * 3;

  if (rem == 0) {
    // EG2: idx in [0,384): z = idx&1, bt = (idx>>1)&7, nx = idx>>4 in [0,24)
    const int idx = grp;
    const int z = idx & 1, bt = (idx >> 1) & 7, nx = idx >> 4;
    constexpr int KCH = KD / 2;   // 1536, NSTEP = 48
    gemm_rt_body<false>(h + (size_t)bt * 64 * KD + (size_t)z * KCH,
                        w2 + (size_t)bt * KD * KD + (size_t)z * KCH * KD,
                        KD, KD, KCH / 32, nx * 128, wv, lane, &lw[0][0],
                        ep + ((size_t)z * NE + bt) * 64 * KD, nullptr, nullptr);
  } else {
    // pd: idx in [0,768): b = idx/12, sl = idx%12
    const int idx = grp * 2 + (rem - 1);
    const int b = idx / 12, sl = idx % 12;
    const int base = sl * 1024;
    float (*red)[8] = reinterpret_cast<float(*)[8]>(&lw[0][0]);  // 8 KB

    float p[8] = {0, 0, 0, 0, 0, 0, 0, 0};
    #pragma unroll
    for (int k = 0; k < 4; ++k) {
      const int i = base + k * 256 + t;
      float tv = swb1[i];
      #pragma unroll
      for (int zz = 0; zz < 4; ++zz)
        tv += tpt[(size_t)zz * (64 * ND) + (size_t)b * ND + i];
      tv = gelu_f(tv);
      const float4* wp = reinterpret_cast<const float4*>(sww2 + (size_t)i * 8);
      const float4 wa = wp[0], wc = wp[1];
      p[0] += tv * wa.x; p[1] += tv * wa.y; p[2] += tv * wa.z; p[3] += tv * wa.w;
      p[4] += tv * wc.x; p[5] += tv * wc.y; p[6] += tv * wc.z; p[7] += tv * wc.w;
    }
    #pragma unroll
    for (int e = 0; e < 8; ++e) red[t][e] = p[e];
    __syncthreads();
    for (int off = 128; off >= 1; off >>= 1) {
      if (t < off) {
        #pragma unroll
        for (int e = 0; e < 8; ++e) red[t][e] += red[t + off][e];
      }
      __syncthreads();
    }
    if (t < 8) pd[(size_t)idx * 8 + t] = red[0][t];
  }
}

// ---------------------------------------------------------------------------
// Static skinny GEMM (r2-proven) for the ch chain.
// ---------------------------------------------------------------------------
template<int K, int N, int SPLIT, bool NGUARD>
__global__ __launch_bounds__(256) void gemm2(
    const unsigned short* __restrict__ A, const float* __restrict__ W,
    float* __restrict__ outp, const int nbatch)
{
  constexpr int KCH = K / SPLIT;
  constexpr int NSTEP = KCH / 32;
  __shared__ float lw[2][4096];

  const int t = threadIdx.x;
  const int wv = t >> 6, lane = t & 63;
  const int n0 = blockIdx.x * 128;
  const int bt = blockIdx.y, z = blockIdx.z;

  const unsigned short* Ab = A + (size_t)bt * 64 * K + (size_t)z * KCH;
  const float*          Wb = W + (size_t)bt * (size_t)K * N;

  const int srow = wv * 8 + (lane >> 5);
  const int scol = (((lane & 31) * 4) - wv * 8) & 127;
  const float* gsrc   = Wb + (size_t)(z * KCH + srow) * N + n0 + scol;
  const float* glimit = Wb + (size_t)K * N - 4;
  float* lbase = &lw[0][0] + wv * 1024 + lane * 4;

  auto stage = [&](int bf, int st) {
    const float* g = gsrc + (size_t)st * 32 * N;
    float* l = lbase + bf * 4096;
    #pragma unroll
    for (int r = 0; r < 4; ++r) {
      const float* gp = g + (size_t)(r * 2) * N;
      if (NGUARD && gp > glimit) gp = glimit;
      __builtin_amdgcn_global_load_lds((gvp)gp, (lvp)(l + r * 256), 16, 0, 0);
    }
  };

  const int ln = lane & 15, q = lane >> 4, g8 = q * 8;
  const unsigned short* ap = Ab + (size_t)ln * K + g8;
  const int colp0 = (wv * 32 +      ln + g8) & 127;
  const int colp1 = (wv * 32 + 16 + ln + g8) & 127;

  f32x4 acc[4][2];
  #pragma unroll
  for (int mt = 0; mt < 4; ++mt) {
    acc[mt][0] = (f32x4){0.f, 0.f, 0.f, 0.f};
    acc[mt][1] = (f32x4){0.f, 0.f, 0.f, 0.f};
  }

  stage(0, 0);
  for (int st = 0; st < NSTEP; ++st) {
    const int bf = st & 1;
    __syncthreads();
    if (st + 1 < NSTEP) stage(bf ^ 1, st + 1);

    const float* lb = &lw[bf][0];
    union { short8 v; unsigned short u[8]; } pb0, pb1;
    #pragma unroll
    for (int j = 0; j < 8; ++j) {
      pb0.u[j] = f2bf(lb[(g8 + j) * 128 + colp0]);
      pb1.u[j] = f2bf(lb[(g8 + j) * 128 + colp1]);
    }
    #pragma unroll
    for (int mt = 0; mt < 4; ++mt) {
      const short8 afr = *reinterpret_cast<const short8*>(ap + (size_t)mt * 16 * K + st * 32);
      acc[mt][0] = __builtin_amdgcn_mfma_f32_16x16x32_bf16(afr, pb0.v, acc[mt][0], 0, 0, 0);
      acc[mt][1] = __builtin_amdgcn_mfma_f32_16x16x32_bf16(afr, pb1.v, acc[mt][1], 0, 0, 0);
    }
  }

  float* op = outp + (size_t)(z * nbatch + bt) * 64 * N;
  #pragma unroll
  for (int mt = 0; mt < 4; ++mt)
    #pragma unroll
    for (int s = 0; s < 2; ++s) {
      const int col = n0 + wv * 32 + s * 16 + ln;
      if (NGUARD && col >= N) continue;
      #pragma unroll
      for (int r = 0; r < 4; ++r)
        op[(size_t)(mt * 16 + q * 4 + r) * N + col] = acc[mt][s][r];
    }
}

// ---------------------------------------------------------------------------
// Split-K reduce epilogue: out = act(sum_z part[z] + bias[bt][n])
// ---------------------------------------------------------------------------
template<int SPLIT, bool GELU, bool OUTBF>
__global__ __launch_bounds__(256) void reduce_ep(
    const float* __restrict__ part, const float* __restrict__ bias,
    void* __restrict__ outv, const int N, const int nbatch)
{
  const int total = nbatch * 64 * N;
  const int idx = blockIdx.x * 256 + threadIdx.x;
  if (idx >= total) return;
  const int n = idx % N;
  const int bt = idx / (64 * N);
  float s = 0.f;
  #pragma unroll
  for (int zz = 0; zz < SPLIT; ++zz) s += part[(size_t)zz * total + idx];
  s += bias[(size_t)bt * N + n];
  if (GELU) s = gelu_f(s);
  if (OUTBF) ((unsigned short*)outv)[idx] = f2bf(s);
  else       ((float*)outv)[idx] = s;
}

// ---------------------------------------------------------------------------
// Fused gate-softmax + expert-reduce + mix (z2 partials):
// lg[e] = sum_sl pd[b][sl][e] + sw_b2[e]; w = softmax(lg)
// ws[b][c] = sum_e w[e] * (sum_z ep[((z*8+e)*64+b)*KD + c] + b2[e][c])
// ---------------------------------------------------------------------------
__global__ __launch_bounds__(256) void mix2s_kernel(
    const float* __restrict__ ep, const float* __restrict__ b2,
    const float* __restrict__ pd, const float* __restrict__ swb2,
    unsigned short* __restrict__ wsb)
{
  const int idx = blockIdx.x * 256 + threadIdx.x;   // 64*KD total
  const int b = idx / KD, c = idx % KD;

  float lg[8];
  #pragma unroll
  for (int e = 0; e < 8; ++e) lg[e] = swb2[e];
  for (int sl = 0; sl < 12; ++sl)
    #pragma unroll
    for (int e = 0; e < 8; ++e) lg[e] += pd[((size_t)b * 12 + sl) * 8 + e];
  float mx = lg[0];
  #pragma unroll
  for (int e = 1; e < 8; ++e) mx = fmaxf(mx, lg[e]);
  float sum = 0.f;
  float w[8];
  #pragma unroll
  for (int e = 0; e < 8; ++e) { w[e] = expf(lg[e] - mx); sum += w[e]; }
  const float inv = 1.f / sum;

  float s = 0.f;
  #pragma unroll
  for (int e = 0; e < NE; ++e) {
    float v = b2[(size_t)e * KD + c];
    #pragma unroll
    for (int zz = 0; zz < 2; ++zz)
      v += ep[((size_t)(zz * NE + e) * NB + b) * KD + c];
    s += v * (w[e] * inv);
  }
  wsb[idx] = f2bf(s);
}

// ---------------------------------------------------------------------------
extern "C" void kernel_launch(void* const* d_in, const int* in_sizes, int n_in,
                              void* d_out, int out_size, void* d_ws, size_t ws_size,
                              hipStream_t stream)
{
  (void)in_sizes; (void)n_in; (void)out_size; (void)ws_size;
  const float* x     = (const float*)d_in[0];
  const float* emb   = (const float*)d_in[1];
  const float* w1    = (const float*)d_in[2];
  const float* b1    = (const float*)d_in[3];
  const float* w2    = (const float*)d_in[4];
  const float* b2    = (const float*)d_in[5];
  const float* sw_w1 = (const float*)d_in[6];
  const float* sw_b1 = (const float*)d_in[7];
  const float* sw_w2 = (const float*)d_in[8];
  const float* sw_b2 = (const float*)d_in[9];
  const float* ch_w1 = (const float*)d_in[10];
  const float* ch_b1 = (const float*)d_in[11];
  const float* ch_w2 = (const float*)d_in[12];
  const float* ch_b2 = (const float*)d_in[13];
  float* out = (float*)d_out;

  char* ws = (char*)d_ws;
  size_t off = 0;
  auto alloc = [&](size_t bytes) -> void* {
    void* p = ws + off;
    off += (bytes + 255) & ~(size_t)255;
    return p;
  };
  unsigned short* sel  = (unsigned short*)alloc((size_t)NE * NB * KD * 2);  // bf16 (E,64,KD)
  unsigned short* xb   = (unsigned short*)alloc((size_t)NB * ND * 2);       // bf16 (64,ND)
  unsigned short* h    = (unsigned short*)alloc((size_t)NE * NB * KD * 2);  // bf16 (E,64,KD)
  float*          ep   = (float*)alloc((size_t)2 * NE * NB * KD * 4);       // EG2 partials (z2)
  float*          tpt  = (float*)alloc((size_t)4 * NB * ND * 4);            // sw1 partials (z4)
  float*          pd   = (float*)alloc((size_t)NB * 12 * 8 * 4);            // gate partial dots
  unsigned short* wsb  = (unsigned short*)alloc((size_t)NB * KD * 2);       // bf16 (64,KD)
  float*          g1p  = (float*)alloc((size_t)16 * NB * KD * 4);           // ch1 partials (z16)
  unsigned short* g1   = (unsigned short*)alloc((size_t)NB * KD * 2);       // bf16 (64,KD)
  float*          g2p  = (float*)alloc((size_t)32 * NB * NC * 4);           // ch2 partials (z32)

  // 1) routing + gathers + bf16 casts
  routing_kernel<<<dim3(64), 256, 0, stream>>>(x, emb, sel, xb);
  // 2) Phase A: EG1 (fused gelu -> h) + sw GEMM1 (z4 -> tpt), 576 uniform blocks
  dualA_kernel<<<dim3(576), 256, 0, stream>>>(sel, w1, b1, h, xb, sw_w1, tpt);
  // 3) Phase B: EG2 (z2 -> ep) + gate partial dots (tpt -> pd), 1152 blocks
  dualB_kernel<<<dim3(1152), 256, 0, stream>>>(h, w2, ep, tpt, sw_b1, sw_w2, pd);
  // 4) fused gate-softmax + expert reduce + mix  [bf16]
  mix2s_kernel<<<dim3((NB * KD) / 256), 256, 0, stream>>>(ep, b2, pd, sw_b2, wsb);
  // 5) ch GEMM1 partials: g1p = wsb @ ch_w1 (z16, 384 blocks)
  gemm2<KD, KD, 16, false><<<dim3(24, 1, 16), 256, 0, stream>>>(wsb, ch_w1, g1p, 1);
  // 6) g1 = gelu(sum_z g1p + ch_b1)  [bf16]
  reduce_ep<16, true, true><<<dim3(768), 256, 0, stream>>>(g1p, ch_b1, (void*)g1, KD, 1);
  // 7) ch GEMM2 partials (N=1000, guarded): g2p = g1 @ ch_w2 (z32, 256 blocks)
  gemm2<KD, NC, 32, true><<<dim3(8, 1, 32), 256, 0, stream>>>(g1, ch_w2, g2p, 1);
  // 8) out = sum_z g2p + ch_b2  [f32 -> d_out]
  reduce_ep<32, false, false><<<dim3((NB * NC + 255) / 256), 256, 0, stream>>>(g2p, ch_b2, (void*)out, NC, 1);
}

// Round 11
// 349.826 us; speedup vs baseline: 1.1223x; 1.1223x over previous
//
#include <hip/hip_runtime.h>
#include <hip/hip_bf16.h>

using short8 = __attribute__((ext_vector_type(8))) short;
using f32x4  = __attribute__((ext_vector_type(4))) float;

typedef const __attribute__((address_space(1))) void* gvp;
typedef __attribute__((address_space(3))) void* lvp;

#define NB   64     // batch rows (M)
#define NTOK 32     // tokens per batch row
#define DD   384
#define NE   8      // experts
#define TK   8      // top-k
#define NC   1000
#define KD   3072   // K*D
#define ND   12288  // N*D

__device__ __forceinline__ float gelu_f(float x) {
  return 0.5f * x * (1.0f + erff(x * 0.70710678118654752440f));
}

// f32 -> bf16 round-to-nearest-even (bit trick)
__device__ __forceinline__ unsigned short f2bf(float f) {
  unsigned u = __float_as_uint(f);
  u += 0x7fffu + ((u >> 16) & 1u);
  return (unsigned short)(u >> 16);
}

// ---------------------------------------------------------------------------
// Routing: logits = x[b] @ emb^T, top-8 per (b,e) (softmax monotonic -> skip),
// gather sel[e][b][k*D+d] = bf16(x[b][I[b,e,k]][d]); also xb = bf16(x).
// ---------------------------------------------------------------------------
__global__ __launch_bounds__(256) void routing_kernel(
    const float* __restrict__ x, const float* __restrict__ emb,
    unsigned short* __restrict__ sel, unsigned short* __restrict__ xb)
{
  __shared__ float xs[NTOK][DD + 1];   // +1 pad: kill stride-384 bank conflicts
  __shared__ float es[NE][DD + 1];
  __shared__ float lg[NE][NTOK];
  __shared__ int   Is[NE][TK];
  const int b = blockIdx.x, tid = threadIdx.x;

  for (int i = tid; i < NTOK * DD; i += 256) xs[i / DD][i % DD] = x[(size_t)b * ND + i];
  for (int i = tid; i < NE * DD;   i += 256) es[i / DD][i % DD] = emb[i];
  __syncthreads();

  {
    const int e = tid >> 5, n = tid & 31;
    float s = 0.f;
    for (int d = 0; d < DD; ++d) s += xs[n][d] * es[e][d];
    lg[e][n] = s;
  }
  __syncthreads();

  if (tid < NE) {   // stable argmax x8: ties -> lowest index, matches lax.top_k
    const int e = tid;
    for (int k = 0; k < TK; ++k) {
      float best = lg[e][0]; int bi = 0;
      for (int n = 1; n < NTOK; ++n) { float v = lg[e][n]; if (v > best) { best = v; bi = n; } }
      Is[e][k] = bi;
      lg[e][bi] = -INFINITY;
    }
  }
  __syncthreads();

  for (int i = tid; i < NE * KD; i += 256) {
    const int e = i / KD, r = i % KD, k = r / DD, d = r % DD;
    const int n = Is[e][k];
    sel[((size_t)e * NB + b) * KD + r] = f2bf(xs[n][d]);
  }
  for (int i = tid; i < ND; i += 256) xb[(size_t)b * ND + i] = f2bf(xs[i / DD][i % DD]);
}

// ---------------------------------------------------------------------------
// Runtime-parameter GEMM body (r2's proven 64x128 double-buffer schedule):
// partial = A(bf16,[64][K],row-stride K, pre-offset to bt,z) @ W(f32, pre-
// offset to z-slice) over NSTEP 32-row steps. global_load_lds width-16,
// rotation swizzle on source addr (linear LDS dest), same rotation on read.
// ---------------------------------------------------------------------------
__device__ __forceinline__ void gemm_rt_body(
    const unsigned short* __restrict__ Ab, const float* __restrict__ Wz,
    float* __restrict__ op, const int K, const int N, const int NSTEP,
    const int n0, const int wv, const int lane, float* __restrict__ lw)
{
  // staging geometry: instr r of wave wv -> rows wv*8 + r*2 + (lane>>5),
  // stored col (lane&31)*4; source col = (stored - wv*8) & 127
  const int srow = wv * 8 + (lane >> 5);
  const int scol = (((lane & 31) * 4) - wv * 8) & 127;
  const float* gsrc = Wz + (size_t)srow * N + n0 + scol;
  float* lbase = lw + wv * 1024 + lane * 4;

  auto stage = [&](int bf, int st) {
    const float* g = gsrc + (size_t)st * 32 * N;
    float* l = lbase + bf * 4096;
    #pragma unroll
    for (int r = 0; r < 4; ++r)
      __builtin_amdgcn_global_load_lds((gvp)(g + (size_t)(r * 2) * N),
                                       (lvp)(l + r * 256), 16, 0, 0);
  };

  const int ln = lane & 15, q = lane >> 4, g8 = q * 8;
  const unsigned short* ap = Ab + (size_t)ln * K + g8;
  const int colp0 = (wv * 32 +      ln + g8) & 127;
  const int colp1 = (wv * 32 + 16 + ln + g8) & 127;

  f32x4 acc[4][2];
  #pragma unroll
  for (int mt = 0; mt < 4; ++mt) {
    acc[mt][0] = (f32x4){0.f, 0.f, 0.f, 0.f};
    acc[mt][1] = (f32x4){0.f, 0.f, 0.f, 0.f};
  }

  stage(0, 0);
  for (int st = 0; st < NSTEP; ++st) {
    const int bf = st & 1;
    __syncthreads();                      // drains stage(st); readers of bf^1 done
    if (st + 1 < NSTEP) stage(bf ^ 1, st + 1);

    const float* lb = lw + bf * 4096;
    union { short8 v; unsigned short u[8]; } pb0, pb1;
    #pragma unroll
    for (int j = 0; j < 8; ++j) {
      pb0.u[j] = f2bf(lb[(g8 + j) * 128 + colp0]);
      pb1.u[j] = f2bf(lb[(g8 + j) * 128 + colp1]);
    }
    #pragma unroll
    for (int mt = 0; mt < 4; ++mt) {
      const short8 afr = *reinterpret_cast<const short8*>(ap + (size_t)mt * 16 * K + st * 32);
      acc[mt][0] = __builtin_amdgcn_mfma_f32_16x16x32_bf16(afr, pb0.v, acc[mt][0], 0, 0, 0);
      acc[mt][1] = __builtin_amdgcn_mfma_f32_16x16x32_bf16(afr, pb1.v, acc[mt][1], 0, 0, 0);
    }
  }

  // epilogue: f32 partial store (C/D: col=ln, row=q*4+reg)
  #pragma unroll
  for (int mt = 0; mt < 4; ++mt)
    #pragma unroll
    for (int s = 0; s < 2; ++s) {
      const int col = n0 + wv * 32 + s * 16 + ln;
      #pragma unroll
      for (int r = 0; r < 4; ++r)
        op[(size_t)(mt * 16 + q * 4 + r) * N + col] = acc[mt][s][r];
    }
}

// ---------------------------------------------------------------------------
// Merged dual-GEMM dispatch, UNIFORM block length (NSTEP=48 both halves):
//   expert GEMM z=2 (KCH=1536): 2 z x 8 bt x 24 ntile = 384 blocks
//   sw GEMM quartet PHASE*4..+3 (KCH=1536): 4 z x 96 ntile = 384 blocks
// 768 identical-length blocks, all co-resident (LDS limit 5 blk/CU -> 1280).
// 1:1 interleave spreads the two read streams across XCDs.
// ---------------------------------------------------------------------------
template<int PHASE>
__global__ __launch_bounds__(256) void dual_gemm(
    const unsigned short* __restrict__ EA, const float* __restrict__ EW,
    float* __restrict__ EO,
    const unsigned short* __restrict__ xb, const float* __restrict__ sww1,
    float* __restrict__ tpt)
{
  __shared__ float lw[2][4096];
  const int t = threadIdx.x, wv = t >> 6, lane = t & 63;
  const int bid = blockIdx.x;
  const int grp = bid >> 1, rem = bid & 1;

  if (rem == 0) {
    // expert GEMM: idx in [0,384): z = idx&1, bt = (idx>>1)&7, nx = idx>>4
    const int idx = grp;
    const int z = idx & 1, bt = (idx >> 1) & 7, nx = idx >> 4;   // nx in [0,24)
    constexpr int KCH = KD / 2;   // 1536, NSTEP = 48
    gemm_rt_body(EA + (size_t)bt * 64 * KD + (size_t)z * KCH,
                 EW + (size_t)bt * KD * KD + (size_t)z * KCH * KD,
                 EO + ((size_t)z * NE + bt) * 64 * KD,
                 KD, KD, KCH / 32, nx * 128, wv, lane, &lw[0][0]);
  } else {
    // sw GEMM quartet: idx in [0,384): z = PHASE*4 + (idx&3), nx = idx>>2
    const int idx = grp;
    const int z = PHASE * 4 + (idx & 3), nx = idx >> 2;          // nx in [0,96)
    constexpr int KCH = ND / 8;   // 1536, NSTEP = 48
    gemm_rt_body(xb + (size_t)z * KCH,
                 sww1 + (size_t)z * KCH * ND,
                 tpt + (size_t)z * 64 * ND,
                 ND, ND, KCH / 32, nx * 128, wv, lane, &lw[0][0]);
  }
}

// ---------------------------------------------------------------------------
// Static skinny GEMM (r2-proven) for the ch chain.
// ---------------------------------------------------------------------------
template<int K, int N, int SPLIT, bool NGUARD>
__global__ __launch_bounds__(256) void gemm2(
    const unsigned short* __restrict__ A, const float* __restrict__ W,
    float* __restrict__ outp, const int nbatch)
{
  constexpr int KCH = K / SPLIT;
  constexpr int NSTEP = KCH / 32;
  __shared__ float lw[2][4096];

  const int t = threadIdx.x;
  const int wv = t >> 6, lane = t & 63;
  const int n0 = blockIdx.x * 128;
  const int bt = blockIdx.y, z = blockIdx.z;

  const unsigned short* Ab = A + (size_t)bt * 64 * K + (size_t)z * KCH;
  const float*          Wb = W + (size_t)bt * (size_t)K * N;

  const int srow = wv * 8 + (lane >> 5);
  const int scol = (((lane & 31) * 4) - wv * 8) & 127;
  const float* gsrc   = Wb + (size_t)(z * KCH + srow) * N + n0 + scol;
  const float* glimit = Wb + (size_t)K * N - 4;
  float* lbase = &lw[0][0] + wv * 1024 + lane * 4;

  auto stage = [&](int bf, int st) {
    const float* g = gsrc + (size_t)st * 32 * N;
    float* l = lbase + bf * 4096;
    #pragma unroll
    for (int r = 0; r < 4; ++r) {
      const float* gp = g + (size_t)(r * 2) * N;
      if (NGUARD && gp > glimit) gp = glimit;
      __builtin_amdgcn_global_load_lds((gvp)gp, (lvp)(l + r * 256), 16, 0, 0);
    }
  };

  const int ln = lane & 15, q = lane >> 4, g8 = q * 8;
  const unsigned short* ap = Ab + (size_t)ln * K + g8;
  const int colp0 = (wv * 32 +      ln + g8) & 127;
  const int colp1 = (wv * 32 + 16 + ln + g8) & 127;

  f32x4 acc[4][2];
  #pragma unroll
  for (int mt = 0; mt < 4; ++mt) {
    acc[mt][0] = (f32x4){0.f, 0.f, 0.f, 0.f};
    acc[mt][1] = (f32x4){0.f, 0.f, 0.f, 0.f};
  }

  stage(0, 0);
  for (int st = 0; st < NSTEP; ++st) {
    const int bf = st & 1;
    __syncthreads();
    if (st + 1 < NSTEP) stage(bf ^ 1, st + 1);

    const float* lb = &lw[bf][0];
    union { short8 v; unsigned short u[8]; } pb0, pb1;
    #pragma unroll
    for (int j = 0; j < 8; ++j) {
      pb0.u[j] = f2bf(lb[(g8 + j) * 128 + colp0]);
      pb1.u[j] = f2bf(lb[(g8 + j) * 128 + colp1]);
    }
    #pragma unroll
    for (int mt = 0; mt < 4; ++mt) {
      const short8 afr = *reinterpret_cast<const short8*>(ap + (size_t)mt * 16 * K + st * 32);
      acc[mt][0] = __builtin_amdgcn_mfma_f32_16x16x32_bf16(afr, pb0.v, acc[mt][0], 0, 0, 0);
      acc[mt][1] = __builtin_amdgcn_mfma_f32_16x16x32_bf16(afr, pb1.v, acc[mt][1], 0, 0, 0);
    }
  }

  float* op = outp + (size_t)(z * nbatch + bt) * 64 * N;
  #pragma unroll
  for (int mt = 0; mt < 4; ++mt)
    #pragma unroll
    for (int s = 0; s < 2; ++s) {
      const int col = n0 + wv * 32 + s * 16 + ln;
      if (NGUARD && col >= N) continue;
      #pragma unroll
      for (int r = 0; r < 4; ++r)
        op[(size_t)(mt * 16 + q * 4 + r) * N + col] = acc[mt][s][r];
    }
}

// ---------------------------------------------------------------------------
// Split-K reduce epilogue: out = act(sum_z part[z] + bias[bt][n])
// ---------------------------------------------------------------------------
template<int SPLIT, bool GELU, bool OUTBF>
__global__ __launch_bounds__(256) void reduce_ep(
    const float* __restrict__ part, const float* __restrict__ bias,
    void* __restrict__ outv, const int N, const int nbatch)
{
  const int total = nbatch * 64 * N;
  const int idx = blockIdx.x * 256 + threadIdx.x;
  if (idx >= total) return;
  const int n = idx % N;
  const int bt = idx / (64 * N);
  float s = 0.f;
  #pragma unroll
  for (int zz = 0; zz < SPLIT; ++zz) s += part[(size_t)zz * total + idx];
  s += bias[(size_t)bt * N + n];
  if (GELU) s = gelu_f(s);
  if (OUTBF) ((unsigned short*)outv)[idx] = f2bf(s);
  else       ((float*)outv)[idx] = s;
}

// ---------------------------------------------------------------------------
// sw gate partial dots (768 blocks = 64 b x 12 slices of 1024):
// pd[b][slice][e] = sum_{i in slice} gelu(sw_b1[i] + sum_z tpt[z][b][i]) * w2[i][e]
// ---------------------------------------------------------------------------
__global__ __launch_bounds__(256) void sw1part_kernel(
    const float* __restrict__ tpt, const float* __restrict__ b1,
    const float* __restrict__ w2, float* __restrict__ pd)
{
  __shared__ float red[256][8];
  const int blk = blockIdx.x, tid = threadIdx.x;
  const int b = blk / 12, sl = blk % 12;
  const int base = sl * 1024;

  float p[8] = {0, 0, 0, 0, 0, 0, 0, 0};
  #pragma unroll
  for (int k = 0; k < 4; ++k) {
    const int i = base + k * 256 + tid;
    float tv = b1[i];
    #pragma unroll
    for (int zz = 0; zz < 8; ++zz)
      tv += tpt[(size_t)zz * (64 * ND) + (size_t)b * ND + i];
    tv = gelu_f(tv);
    const float4* wp = reinterpret_cast<const float4*>(w2 + (size_t)i * 8);
    const float4 wa = wp[0], wc = wp[1];
    p[0] += tv * wa.x; p[1] += tv * wa.y; p[2] += tv * wa.z; p[3] += tv * wa.w;
    p[4] += tv * wc.x; p[5] += tv * wc.y; p[6] += tv * wc.z; p[7] += tv * wc.w;
  }
  #pragma unroll
  for (int e = 0; e < 8; ++e) red[tid][e] = p[e];
  __syncthreads();
  for (int off = 128; off >= 1; off >>= 1) {
    if (tid < off) {
      #pragma unroll
      for (int e = 0; e < 8; ++e) red[tid][e] += red[tid + off][e];
    }
    __syncthreads();
  }
  if (tid < 8) pd[(size_t)blk * 8 + tid] = red[0][tid];
}

// ---------------------------------------------------------------------------
// Fused gate-softmax + expert-reduce + mix (z2 partials):
// lg[e] = sum_sl pd[b][sl][e] + sw_b2[e]; w = softmax(lg)
// ws[b][c] = sum_e w[e] * (sum_z ep[((z*8+e)*64+b)*KD + c] + b2[e][c])
// ---------------------------------------------------------------------------
__global__ __launch_bounds__(256) void mix2s_kernel(
    const float* __restrict__ ep, const float* __restrict__ b2,
    const float* __restrict__ pd, const float* __restrict__ swb2,
    unsigned short* __restrict__ wsb)
{
  const int idx = blockIdx.x * 256 + threadIdx.x;   // 64*KD total
  const int b = idx / KD, c = idx % KD;

  float lg[8];
  #pragma unroll
  for (int e = 0; e < 8; ++e) lg[e] = swb2[e];
  for (int sl = 0; sl < 12; ++sl)
    #pragma unroll
    for (int e = 0; e < 8; ++e) lg[e] += pd[((size_t)b * 12 + sl) * 8 + e];
  float mx = lg[0];
  #pragma unroll
  for (int e = 1; e < 8; ++e) mx = fmaxf(mx, lg[e]);
  float sum = 0.f;
  float w[8];
  #pragma unroll
  for (int e = 0; e < 8; ++e) { w[e] = expf(lg[e] - mx); sum += w[e]; }
  const float inv = 1.f / sum;

  float s = 0.f;
  #pragma unroll
  for (int e = 0; e < NE; ++e) {
    float v = b2[(size_t)e * KD + c];
    #pragma unroll
    for (int zz = 0; zz < 2; ++zz)
      v += ep[((size_t)(zz * NE + e) * NB + b) * KD + c];
    s += v * (w[e] * inv);
  }
  wsb[idx] = f2bf(s);
}

// ---------------------------------------------------------------------------
extern "C" void kernel_launch(void* const* d_in, const int* in_sizes, int n_in,
                              void* d_out, int out_size, void* d_ws, size_t ws_size,
                              hipStream_t stream)
{
  (void)in_sizes; (void)n_in; (void)out_size; (void)ws_size;
  const float* x     = (const float*)d_in[0];
  const float* emb   = (const float*)d_in[1];
  const float* w1    = (const float*)d_in[2];
  const float* b1    = (const float*)d_in[3];
  const float* w2    = (const float*)d_in[4];
  const float* b2    = (const float*)d_in[5];
  const float* sw_w1 = (const float*)d_in[6];
  const float* sw_b1 = (const float*)d_in[7];
  const float* sw_w2 = (const float*)d_in[8];
  const float* sw_b2 = (const float*)d_in[9];
  const float* ch_w1 = (const float*)d_in[10];
  const float* ch_b1 = (const float*)d_in[11];
  const float* ch_w2 = (const float*)d_in[12];
  const float* ch_b2 = (const float*)d_in[13];
  float* out = (float*)d_out;

  char* ws = (char*)d_ws;
  size_t off = 0;
  auto alloc = [&](size_t bytes) -> void* {
    void* p = ws + off;
    off += (bytes + 255) & ~(size_t)255;
    return p;
  };
  unsigned short* sel  = (unsigned short*)alloc((size_t)NE * NB * KD * 2);  // bf16 (E,64,KD)
  unsigned short* xb   = (unsigned short*)alloc((size_t)NB * ND * 2);       // bf16 (64,ND)
  unsigned short* h    = (unsigned short*)alloc((size_t)NE * NB * KD * 2);  // bf16 (E,64,KD)
  float*          ep   = (float*)alloc((size_t)2 * NE * NB * KD * 4);       // expert partials (z2)
  float*          tpt  = (float*)alloc((size_t)8 * NB * ND * 4);            // sw1 partials (z8)
  float*          pd   = (float*)alloc((size_t)NB * 12 * 8 * 4);            // gate partial dots
  unsigned short* wsb  = (unsigned short*)alloc((size_t)NB * KD * 2);       // bf16 (64,KD)
  float*          g1p  = (float*)alloc((size_t)16 * NB * KD * 4);           // ch1 partials (z16)
  unsigned short* g1   = (unsigned short*)alloc((size_t)NB * KD * 2);       // bf16 (64,KD)
  float*          g2p  = (float*)alloc((size_t)32 * NB * NC * 4);           // ch2 partials (z32)

  // 1) routing + gathers + bf16 casts
  routing_kernel<<<dim3(64), 256, 0, stream>>>(x, emb, sel, xb);
  // 2) MERGED uniform: expert GEMM1 (z2, 384 blk) + sw GEMM1 z0-3 (384 blk)
  dual_gemm<0><<<dim3(768), 256, 0, stream>>>(sel, w1, ep, xb, sw_w1, tpt);
  // 3) h = gelu(sum_z ep + b1)  [bf16]
  reduce_ep<2, true, true><<<dim3(6144), 256, 0, stream>>>(ep, b1, (void*)h, KD, 8);
  // 4) MERGED uniform: expert GEMM2 (z2, reuse ep) + sw GEMM1 z4-7 (384 blk)
  dual_gemm<1><<<dim3(768), 256, 0, stream>>>(h, w2, ep, xb, sw_w1, tpt);
  // 5) gate partial dots (768 blocks)
  sw1part_kernel<<<dim3(768), 256, 0, stream>>>(tpt, sw_b1, sw_w2, pd);
  // 6) fused gate-softmax + expert reduce + mix  [bf16]
  mix2s_kernel<<<dim3((NB * KD) / 256), 256, 0, stream>>>(ep, b2, pd, sw_b2, wsb);
  // 7) ch GEMM1 partials: g1p = wsb @ ch_w1 (z16, 384 blocks)
  gemm2<KD, KD, 16, false><<<dim3(24, 1, 16), 256, 0, stream>>>(wsb, ch_w1, g1p, 1);
  // 8) g1 = gelu(sum_z g1p + ch_b1)  [bf16]
  reduce_ep<16, true, true><<<dim3(768), 256, 0, stream>>>(g1p, ch_b1, (void*)g1, KD, 1);
  // 9) ch GEMM2 partials (N=1000, guarded): g2p = g1 @ ch_w2 (z32, 256 blocks)
  gemm2<KD, NC, 32, true><<<dim3(8, 1, 32), 256, 0, stream>>>(g1, ch_w2, g2p, 1);
  // 10) out = sum_z g2p + ch_b2  [f32 -> d_out]
  reduce_ep<32, false, false><<<dim3((NB * NC + 255) / 256), 256, 0, stream>>>(g2p, ch_b2, (void*)out, NC, 1);
}